// Round 20
// baseline (240.615 us; speedup 1.0000x reference)
//
#include <hip/hip_runtime.h>

#define NN 50000
#define NE 800000
#define HD 128
#define NG 256
#define ELLW 64
#define NBUCK 196           /* ceil(50000/256) buckets of 256 nodes */
#define BCAP 4736           /* bucket capacity: mean 4096, +10 sigma */
#define CSTRIDE 16          /* cursor padding: one per 64B line */
#define EPT 16              /* edges per thread in scatter blocks */
#define EPB (256 * EPT)     /* 4096 edges per scatter block */
#define NB_GEMM ((NN + 63) / 64)
#define NB_SCAT ((NE + EPB - 1) / EPB)

__device__ __forceinline__ unsigned f32_to_bf16_rne(float f) {
  unsigned u = __float_as_uint(f);
  return (u + 0x7fffu + ((u >> 16) & 1u)) >> 16;
}

// gemm tile compute from f32 LDS tile: out_bf16[r][c] = bf16((xs@W)[r][c] * (scale?rsqrt(deg[r]+1):1))
__device__ __forceinline__ void gemm_tile(const float* xs, const float* __restrict__ W,
                                          const int* __restrict__ deg, ushort* __restrict__ out,
                                          int row0, int t, bool scale) {
  int lane = t & 31;
  int rg = t >> 5;
  const float4* W4 = (const float4*)W;
  float acc[8][4] = {};
#pragma unroll 2
  for (int k = 0; k < 128; k += 4) {
    float4 b[4];
#pragma unroll
    for (int kk = 0; kk < 4; ++kk) b[kk] = W4[(size_t)(k + kk) * 32 + lane];
    float4 a[8];
#pragma unroll
    for (int i = 0; i < 8; ++i) a[i] = *(const float4*)&xs[(rg * 8 + i) * 128 + k];
#pragma unroll
    for (int i = 0; i < 8; ++i) {
      acc[i][0] = fmaf(a[i].x, b[0].x, acc[i][0]);
      acc[i][1] = fmaf(a[i].x, b[0].y, acc[i][1]);
      acc[i][2] = fmaf(a[i].x, b[0].z, acc[i][2]);
      acc[i][3] = fmaf(a[i].x, b[0].w, acc[i][3]);
      acc[i][0] = fmaf(a[i].y, b[1].x, acc[i][0]);
      acc[i][1] = fmaf(a[i].y, b[1].y, acc[i][1]);
      acc[i][2] = fmaf(a[i].y, b[1].z, acc[i][2]);
      acc[i][3] = fmaf(a[i].y, b[1].w, acc[i][3]);
      acc[i][0] = fmaf(a[i].z, b[2].x, acc[i][0]);
      acc[i][1] = fmaf(a[i].z, b[2].y, acc[i][1]);
      acc[i][2] = fmaf(a[i].z, b[2].z, acc[i][2]);
      acc[i][3] = fmaf(a[i].z, b[2].w, acc[i][3]);
      acc[i][0] = fmaf(a[i].w, b[3].x, acc[i][0]);
      acc[i][1] = fmaf(a[i].w, b[3].y, acc[i][1]);
      acc[i][2] = fmaf(a[i].w, b[3].z, acc[i][2]);
      acc[i][3] = fmaf(a[i].w, b[3].w, acc[i][3]);
    }
  }
#pragma unroll
  for (int i = 0; i < 8; ++i) {
    int r = row0 + rg * 8 + i;
    if (r < NN) {
      float d = scale ? rsqrtf((float)(deg[r] + 1)) : 1.0f;
      ushort4 o;
      o.x = (ushort)f32_to_bf16_rne(acc[i][0] * d);
      o.y = (ushort)f32_to_bf16_rne(acc[i][1] * d);
      o.z = (ushort)f32_to_bf16_rne(acc[i][2] * d);
      o.w = (ushort)f32_to_bf16_rne(acc[i][3] * d);
      *(ushort4*)&out[(size_t)r * 128 + lane * 4] = o;
    }
  }
}

// ---------- heterogeneous: gemm1 blocks first; fat LDS-binning scatter blocks backfill ----------
// Scatter block: 4096 edges. Bin by bucket (LDS atomics, lp stored in LDS),
// block-scan, ONE global atomic per (block,bucket) to reserve, re-read edges
// (L2-hot) into bucket-sorted LDS stage, write out in ~84B contiguous runs.
__global__ __launch_bounds__(256) void scatter_gemm_k(const float* __restrict__ X, const float* __restrict__ W1,
                                                      ushort* __restrict__ tmp,
                                                      const int* __restrict__ src, const int* __restrict__ dst,
                                                      const int* __restrict__ batch,
                                                      int* __restrict__ cursor, uint* __restrict__ ebuf,
                                                      int* __restrict__ cnt) {
  __shared__ __align__(16) char smem[32768];
  int t = threadIdx.x;
  if (blockIdx.x < NB_GEMM) {
    float* xs = (float*)smem;
    int row0 = blockIdx.x * 64;
    const float4* X4 = (const float4*)X;
    float4* xs4 = (float4*)xs;
#pragma unroll
    for (int i = 0; i < 8; ++i) {
      int idx = i * 256 + t;
      int r = row0 + (idx >> 5);
      if (r > NN - 1) r = NN - 1;
      xs4[idx] = X4[(size_t)r * 32 + (idx & 31)];
    }
    __syncthreads();
    gemm_tile(xs, W1, nullptr, tmp, row0, t, false);
  } else {
    uint*   stage   = (uint*)smem;                 // [4096]  0..16K
    ushort* meta_lp = (ushort*)(smem + 16384);     // [4096] 16K..24K
    unsigned char* sbuck = (unsigned char*)(smem + 24576); // [4096] 24K..28K
    int*    bcnt  = (int*)(smem + 28672);          // [256] 28K..29K
    int*    scan  = (int*)(smem + 29696);          // [256] 29K..30K
    int*    boff  = (int*)(smem + 30720);          // [256] 30K..31K
    int*    gbase = (int*)(smem + 31744);          // [256] 31K..32K
    bcnt[t] = 0;
    __syncthreads();
    int base = (blockIdx.x - NB_GEMM) * EPB + t;
    // phase 2: bin + record lp
#pragma unroll 4
    for (int k = 0; k < EPT; ++k) {
      int e = base + k * 256;
      if (e < NE) {
        int d = dst[e];
        int bk = d >> 8;
        int lp = atomicAdd(&bcnt[bk], 1);
        meta_lp[k * 256 + t] = (ushort)lp;
      }
      if (e < NN) atomicAdd(&cnt[batch[e]], 1);
    }
    __syncthreads();
    // phase 3: scan + reserve
    int v = bcnt[t];
    scan[t] = v;
    __syncthreads();
    for (int off = 1; off < 256; off <<= 1) {
      int x = (t >= off) ? scan[t - off] : 0;
      __syncthreads();
      scan[t] += x;
      __syncthreads();
    }
    boff[t] = scan[t] - v;
    if (t < NBUCK && v > 0) gbase[t] = atomicAdd(&cursor[t * CSTRIDE], v);
    __syncthreads();
    // phase 4: re-read (L2-hot) -> bucket-sorted stage
#pragma unroll 4
    for (int k = 0; k < EPT; ++k) {
      int e = base + k * 256;
      if (e < NE) {
        int d = dst[e];
        int s = src[e];
        int bk = d >> 8;
        int slot = boff[bk] + (int)meta_lp[k * 256 + t];
        stage[slot] = ((uint)s << 8) | (uint)(d & 255);
        sbuck[slot] = (unsigned char)bk;
      }
    }
    __syncthreads();
    // phase 5: contiguous-run writes
    int ntot = scan[255];
    for (int i = t; i < ntot; i += 256) {
      int b = sbuck[i];
      int pos = gbase[b] + (i - boff[b]);
      if (pos < BCAP) ebuf[(size_t)b * BCAP + pos] = stage[i];
    }
  }
}

// ---------- bucket -> ELL + deg, all scatter in LDS, all global I/O coalesced ----------
__global__ __launch_bounds__(256) void ellbuild_k(const int* __restrict__ cursor, const uint* __restrict__ ebuf,
                                                  int* __restrict__ deg, ushort* __restrict__ ell) {
  __shared__ ushort lell[256 * ELLW];
  __shared__ int lcnt[256];
  int t = threadIdx.x;
  int b = blockIdx.x;
  lcnt[t] = 0;
  __syncthreads();
  int ne = cursor[b * CSTRIDE];
  if (ne > BCAP) ne = BCAP;
  for (int i = t; i < ne; i += 256) {
    uint u = ebuf[(size_t)b * BCAP + i];
    int dl = u & 255;
    int p = atomicAdd(&lcnt[dl], 1);
    if (p < ELLW) lell[dl * ELLW + p] = (ushort)(u >> 8);
  }
  __syncthreads();
  int node = b * 256 + t;
  if (node < NN) deg[node] = lcnt[t];
  const uint* l4 = (const uint*)lell;
  uint* g4 = (uint*)ell;
  for (int idx = t; idx < 256 * 32; idx += 256) {
    int nod = b * 256 + (idx >> 5);
    if (nod < NN) g4[(size_t)nod * 32 + (idx & 31)] = l4[idx];
  }
}

// ---------- GEMM (layer 2): stages bf16 h1 -> f32 LDS, scaled bf16 out ----------
__global__ __launch_bounds__(256) void gemm128_k(const ushort* __restrict__ H, const float* __restrict__ W,
                                                 const int* __restrict__ deg, ushort* __restrict__ out) {
  __shared__ float xs[64 * 128];
  int t = threadIdx.x;
  int row0 = blockIdx.x * 64;
  const uint* H2 = (const uint*)H;
#pragma unroll
  for (int i = 0; i < 16; ++i) {
    int idx = i * 256 + t;
    int r = row0 + (idx >> 6);
    if (r > NN - 1) r = NN - 1;
    int c = idx & 63;
    uint u = H2[(size_t)r * 64 + c];
    float2 f;
    f.x = __uint_as_float(u << 16);
    f.y = __uint_as_float(u & 0xffff0000u);
    *(float2*)&xs[(idx >> 6) * 128 + c * 2] = f;
  }
  __syncthreads();
  gemm_tile(xs, W, deg, out, row0, t, true);
}

// ---------- pull aggregation (measured structure, unchanged) ----------
template <bool POOL, bool SSRC>
__global__ __launch_bounds__(256) void aggregate_k(const ushort* __restrict__ tmp2,
                                                   const ushort* __restrict__ ell, const int* __restrict__ deg,
                                                   const float* __restrict__ bias,
                                                   ushort* __restrict__ out,
                                                   const int* __restrict__ batch, float* __restrict__ sums) {
  int wid = threadIdx.x >> 6;
  int lane = threadIdx.x & 63;
  int n = blockIdx.x * 4 + wid;
  if (n >= NN) return;
  const uint* TU = (const uint*)tmp2;
  int dn = deg[n];
  float dv = rsqrtf((float)(dn + 1));
  uint sv = TU[(size_t)n * 64 + lane];
  float sw = SSRC ? dv : 1.0f;
  float2 acc;
  acc.x = __uint_as_float(sv << 16) * sw;
  acc.y = __uint_as_float(sv & 0xffff0000u) * sw;
  int d = dn; if (d > ELLW) d = ELLW;
  int idx = (int)ell[(size_t)n * ELLW + lane];
  int j = 0;
  for (; j + 8 <= d; j += 8) {
    int s0 = __shfl(idx, j);
    int s1 = __shfl(idx, j + 1);
    int s2 = __shfl(idx, j + 2);
    int s3 = __shfl(idx, j + 3);
    int s4 = __shfl(idx, j + 4);
    int s5 = __shfl(idx, j + 5);
    int s6 = __shfl(idx, j + 6);
    int s7 = __shfl(idx, j + 7);
    float d0 = SSRC ? rsqrtf((float)(deg[s0] + 1)) : 1.0f;
    float d1 = SSRC ? rsqrtf((float)(deg[s1] + 1)) : 1.0f;
    float d2 = SSRC ? rsqrtf((float)(deg[s2] + 1)) : 1.0f;
    float d3 = SSRC ? rsqrtf((float)(deg[s3] + 1)) : 1.0f;
    float d4 = SSRC ? rsqrtf((float)(deg[s4] + 1)) : 1.0f;
    float d5 = SSRC ? rsqrtf((float)(deg[s5] + 1)) : 1.0f;
    float d6 = SSRC ? rsqrtf((float)(deg[s6] + 1)) : 1.0f;
    float d7 = SSRC ? rsqrtf((float)(deg[s7] + 1)) : 1.0f;
    uint v0 = TU[(size_t)s0 * 64 + lane];
    uint v1 = TU[(size_t)s1 * 64 + lane];
    uint v2 = TU[(size_t)s2 * 64 + lane];
    uint v3 = TU[(size_t)s3 * 64 + lane];
    uint v4 = TU[(size_t)s4 * 64 + lane];
    uint v5 = TU[(size_t)s5 * 64 + lane];
    uint v6 = TU[(size_t)s6 * 64 + lane];
    uint v7 = TU[(size_t)s7 * 64 + lane];
    if (SSRC) {
      acc.x = fmaf(__uint_as_float(v0 << 16), d0, acc.x);
      acc.y = fmaf(__uint_as_float(v0 & 0xffff0000u), d0, acc.y);
      acc.x = fmaf(__uint_as_float(v1 << 16), d1, acc.x);
      acc.y = fmaf(__uint_as_float(v1 & 0xffff0000u), d1, acc.y);
      acc.x = fmaf(__uint_as_float(v2 << 16), d2, acc.x);
      acc.y = fmaf(__uint_as_float(v2 & 0xffff0000u), d2, acc.y);
      acc.x = fmaf(__uint_as_float(v3 << 16), d3, acc.x);
      acc.y = fmaf(__uint_as_float(v3 & 0xffff0000u), d3, acc.y);
      acc.x = fmaf(__uint_as_float(v4 << 16), d4, acc.x);
      acc.y = fmaf(__uint_as_float(v4 & 0xffff0000u), d4, acc.y);
      acc.x = fmaf(__uint_as_float(v5 << 16), d5, acc.x);
      acc.y = fmaf(__uint_as_float(v5 & 0xffff0000u), d5, acc.y);
      acc.x = fmaf(__uint_as_float(v6 << 16), d6, acc.x);
      acc.y = fmaf(__uint_as_float(v6 & 0xffff0000u), d6, acc.y);
      acc.x = fmaf(__uint_as_float(v7 << 16), d7, acc.x);
      acc.y = fmaf(__uint_as_float(v7 & 0xffff0000u), d7, acc.y);
    } else {
      float x0 = __uint_as_float(v0 << 16), y0 = __uint_as_float(v0 & 0xffff0000u);
      float x1 = __uint_as_float(v1 << 16), y1 = __uint_as_float(v1 & 0xffff0000u);
      float x2 = __uint_as_float(v2 << 16), y2 = __uint_as_float(v2 & 0xffff0000u);
      float x3 = __uint_as_float(v3 << 16), y3 = __uint_as_float(v3 & 0xffff0000u);
      float x4 = __uint_as_float(v4 << 16), y4 = __uint_as_float(v4 & 0xffff0000u);
      float x5 = __uint_as_float(v5 << 16), y5 = __uint_as_float(v5 & 0xffff0000u);
      float x6 = __uint_as_float(v6 << 16), y6 = __uint_as_float(v6 & 0xffff0000u);
      float x7 = __uint_as_float(v7 << 16), y7 = __uint_as_float(v7 & 0xffff0000u);
      acc.x += ((x0 + x1) + (x2 + x3)) + ((x4 + x5) + (x6 + x7));
      acc.y += ((y0 + y1) + (y2 + y3)) + ((y4 + y5) + (y6 + y7));
    }
  }
  for (; j < d; ++j) {
    int s0 = __shfl(idx, j);
    float d0 = SSRC ? rsqrtf((float)(deg[s0] + 1)) : 1.0f;
    uint v = TU[(size_t)s0 * 64 + lane];
    acc.x = fmaf(__uint_as_float(v << 16), d0, acc.x);
    acc.y = fmaf(__uint_as_float(v & 0xffff0000u), d0, acc.y);
  }
  float2 bb = ((const float2*)bias)[lane];
  float ox = fmaxf(fmaf(acc.x, dv, bb.x), 0.0f);
  float oy = fmaxf(fmaf(acc.y, dv, bb.y), 0.0f);
  if (POOL) {
    int g = batch[n];
    float* sp = &sums[(size_t)g * HD + lane * 2];
    atomicAdd(sp + 0, ox);
    atomicAdd(sp + 1, oy);
  } else {
    uint pk = f32_to_bf16_rne(ox) | (f32_to_bf16_rne(oy) << 16);
    ((uint*)out)[(size_t)n * 64 + lane] = pk;
  }
}

// ---------- head ----------
__global__ __launch_bounds__(128) void mlp_k(const float* __restrict__ sums, const int* __restrict__ cnt,
                                             const float* __restrict__ Wl1, const float* __restrict__ bl1,
                                             const float* __restrict__ Wl2, const float* __restrict__ bl2,
                                             float* __restrict__ out) {
  __shared__ float gs[128];
  __shared__ float red[128];
  int g = blockIdx.x, t = threadIdx.x;
  int c = cnt[g]; if (c < 1) c = 1;
  gs[t] = sums[(size_t)g * HD + t] / (float)c;
  __syncthreads();
  float acc = bl1[t];
#pragma unroll 8
  for (int k = 0; k < 128; ++k) acc = fmaf(gs[k], Wl1[k * HD + t], acc);
  acc = fmaxf(acc, 0.0f);
  red[t] = acc * Wl2[t];
  __syncthreads();
  for (int off = 64; off > 0; off >>= 1) {
    if (t < off) red[t] += red[t + off];
    __syncthreads();
  }
  if (t == 0) out[g] = red[0] + bl2[0];
}

extern "C" void kernel_launch(void* const* d_in, const int* in_sizes, int n_in,
                              void* d_out, int out_size, void* d_ws, size_t ws_size,
                              hipStream_t stream) {
  const float* x   = (const float*)d_in[0];
  const int*   edge = (const int*)d_in[1];
  const int*   batch = (const int*)d_in[2];
  const float* W1  = (const float*)d_in[3];
  const float* b1  = (const float*)d_in[4];
  const float* W2  = (const float*)d_in[5];
  const float* b2  = (const float*)d_in[6];
  const float* Wl1 = (const float*)d_in[7];
  const float* bl1 = (const float*)d_in[8];
  const float* Wl2 = (const float*)d_in[9];
  const float* bl2 = (const float*)d_in[10];
  const int* srcp = edge;
  const int* dstp = edge + NE;

  char* w = (char*)d_ws;
  size_t off = 0;
  auto alloc = [&](size_t bytes) -> void* {
    void* p = w + off;
    off += (bytes + 255) & ~(size_t)255;
    return p;
  };
  // zero region: cursor | cnt | sums (one memset)
  int*    cursor = (int*)alloc((size_t)NBUCK * CSTRIDE * 4);
  int*    cnt    = (int*)alloc(NG * 4);
  float*  sums   = (float*)alloc((size_t)NG * HD * 4);
  size_t zero_bytes = off;
  int*    deg  = (int*)alloc(NN * 4);
  uint*   ebuf = (uint*)alloc((size_t)NBUCK * BCAP * 4);
  ushort* ell  = (ushort*)alloc((size_t)NN * ELLW * 2);
  ushort* tmp  = (ushort*)alloc((size_t)NN * HD * 2);   // bf16 layer-1 out (UNSCALED)
  ushort* h1   = (ushort*)alloc((size_t)NN * HD * 2);   // bf16 h1
  ushort* tmp2 = (ushort*)alloc((size_t)NN * HD * 2);   // bf16 layer-2 out (scaled)

  hipMemsetAsync(cursor, 0, zero_bytes, stream);

  scatter_gemm_k<<<NB_GEMM + NB_SCAT, 256, 0, stream>>>(x, W1, tmp, srcp, dstp, batch, cursor, ebuf, cnt);
  ellbuild_k<<<NBUCK, 256, 0, stream>>>(cursor, ebuf, deg, ell);
  aggregate_k<false, true><<<(NN + 3) / 4, 256, 0, stream>>>(tmp, ell, deg, b1, h1, nullptr, nullptr);
  gemm128_k<<<(NN + 63) / 64, 256, 0, stream>>>(h1, W2, deg, tmp2);
  aggregate_k<true, false><<<(NN + 3) / 4, 256, 0, stream>>>(tmp2, ell, deg, b2, nullptr, batch, sums);
  mlp_k<<<NG, 128, 0, stream>>>(sums, cnt, Wl1, bl1, Wl2, bl2, (float*)d_out);
}

// Round 22
// 226.619 us; speedup vs baseline: 1.0618x; 1.0618x over previous
//
#include <hip/hip_runtime.h>

#define NN 50000
#define NE 800000
#define HD 128
#define NG 256
#define ELLW 64
#define NBUCK 196           /* ceil(50000/256) buckets of 256 nodes */
#define BCAP 4736           /* bucket capacity: mean 4096, +10 sigma */
#define CSTRIDE 16          /* cursor padding: one per 64B line */
#define EPT 8               /* edges per thread in scatter blocks */
#define EPB (256 * EPT)     /* 2048 edges per scatter block */
#define NB_GEMM ((NN + 63) / 64)
#define NB_SCAT ((NE + EPB - 1) / EPB)

__device__ __forceinline__ unsigned f32_to_bf16_rne(float f) {
  unsigned u = __float_as_uint(f);
  return (u + 0x7fffu + ((u >> 16) & 1u)) >> 16;
}

// gemm tile compute from f32 LDS tile: out_bf16[r][c] = bf16((xs@W)[r][c] * (scale?rsqrt(deg[r]+1):1))
__device__ __forceinline__ void gemm_tile(const float* xs, const float* __restrict__ W,
                                          const int* __restrict__ deg, ushort* __restrict__ out,
                                          int row0, int t, bool scale) {
  int lane = t & 31;
  int rg = t >> 5;
  const float4* W4 = (const float4*)W;
  float acc[8][4] = {};
#pragma unroll 2
  for (int k = 0; k < 128; k += 4) {
    float4 b[4];
#pragma unroll
    for (int kk = 0; kk < 4; ++kk) b[kk] = W4[(size_t)(k + kk) * 32 + lane];
    float4 a[8];
#pragma unroll
    for (int i = 0; i < 8; ++i) a[i] = *(const float4*)&xs[(rg * 8 + i) * 128 + k];
#pragma unroll
    for (int i = 0; i < 8; ++i) {
      acc[i][0] = fmaf(a[i].x, b[0].x, acc[i][0]);
      acc[i][1] = fmaf(a[i].x, b[0].y, acc[i][1]);
      acc[i][2] = fmaf(a[i].x, b[0].z, acc[i][2]);
      acc[i][3] = fmaf(a[i].x, b[0].w, acc[i][3]);
      acc[i][0] = fmaf(a[i].y, b[1].x, acc[i][0]);
      acc[i][1] = fmaf(a[i].y, b[1].y, acc[i][1]);
      acc[i][2] = fmaf(a[i].y, b[1].z, acc[i][2]);
      acc[i][3] = fmaf(a[i].y, b[1].w, acc[i][3]);
      acc[i][0] = fmaf(a[i].z, b[2].x, acc[i][0]);
      acc[i][1] = fmaf(a[i].z, b[2].y, acc[i][1]);
      acc[i][2] = fmaf(a[i].z, b[2].z, acc[i][2]);
      acc[i][3] = fmaf(a[i].z, b[2].w, acc[i][3]);
      acc[i][0] = fmaf(a[i].w, b[3].x, acc[i][0]);
      acc[i][1] = fmaf(a[i].w, b[3].y, acc[i][1]);
      acc[i][2] = fmaf(a[i].w, b[3].z, acc[i][2]);
      acc[i][3] = fmaf(a[i].w, b[3].w, acc[i][3]);
    }
  }
#pragma unroll
  for (int i = 0; i < 8; ++i) {
    int r = row0 + rg * 8 + i;
    if (r < NN) {
      float d = scale ? rsqrtf((float)(deg[r] + 1)) : 1.0f;
      ushort4 o;
      o.x = (ushort)f32_to_bf16_rne(acc[i][0] * d);
      o.y = (ushort)f32_to_bf16_rne(acc[i][1] * d);
      o.z = (ushort)f32_to_bf16_rne(acc[i][2] * d);
      o.w = (ushort)f32_to_bf16_rne(acc[i][3] * d);
      *(ushort4*)&out[(size_t)r * 128 + lane * 4] = o;
    }
  }
}

// ---------- heterogeneous: gemm1 blocks first; LDS-binning scatter blocks backfill ----------
// Scatter block: 2048 edges. Bin by bucket (LDS atomics, lp in LDS), block-scan,
// ONE global atomic per (block,bucket), re-read edges (L2-hot) into bucket-sorted
// LDS stage, write out in ~42B contiguous runs.
__global__ __launch_bounds__(256) void scatter_gemm_k(const float* __restrict__ X, const float* __restrict__ W1,
                                                      ushort* __restrict__ tmp,
                                                      const int* __restrict__ src, const int* __restrict__ dst,
                                                      const int* __restrict__ batch,
                                                      int* __restrict__ cursor, uint* __restrict__ ebuf,
                                                      int* __restrict__ cnt) {
  __shared__ __align__(16) char smem[32768];
  int t = threadIdx.x;
  if (blockIdx.x < NB_GEMM) {
    float* xs = (float*)smem;
    int row0 = blockIdx.x * 64;
    const float4* X4 = (const float4*)X;
    float4* xs4 = (float4*)xs;
#pragma unroll
    for (int i = 0; i < 8; ++i) {
      int idx = i * 256 + t;
      int r = row0 + (idx >> 5);
      if (r > NN - 1) r = NN - 1;
      xs4[idx] = X4[(size_t)r * 32 + (idx & 31)];
    }
    __syncthreads();
    gemm_tile(xs, W1, nullptr, tmp, row0, t, false);
  } else {
    uint*   stage   = (uint*)smem;                 // [2048]  0..8K
    ushort* meta_lp = (ushort*)(smem + 8192);      // [2048]  8K..12K
    unsigned char* sbuck = (unsigned char*)(smem + 12288); // [2048] 12K..14K
    int*    bcnt  = (int*)(smem + 14336);          // [256] 14K..15K
    int*    scan  = (int*)(smem + 15360);          // [256] 15K..16K
    int*    boff  = (int*)(smem + 16384);          // [256] 16K..17K
    int*    gbase = (int*)(smem + 17408);          // [256] 17K..18K
    bcnt[t] = 0;
    __syncthreads();
    int base = (blockIdx.x - NB_GEMM) * EPB + t;
    // phase 2: bin + record lp
#pragma unroll 4
    for (int k = 0; k < EPT; ++k) {
      int e = base + k * 256;
      if (e < NE) {
        int d = dst[e];
        int bk = d >> 8;
        int lp = atomicAdd(&bcnt[bk], 1);
        meta_lp[k * 256 + t] = (ushort)lp;
      }
      if (e < NN) atomicAdd(&cnt[batch[e]], 1);
    }
    __syncthreads();
    // phase 3: scan + reserve
    int v = bcnt[t];
    scan[t] = v;
    __syncthreads();
    for (int off = 1; off < 256; off <<= 1) {
      int x = (t >= off) ? scan[t - off] : 0;
      __syncthreads();
      scan[t] += x;
      __syncthreads();
    }
    boff[t] = scan[t] - v;
    if (t < NBUCK && v > 0) gbase[t] = atomicAdd(&cursor[t * CSTRIDE], v);
    __syncthreads();
    // phase 4: re-read (L2-hot) -> bucket-sorted stage
#pragma unroll 4
    for (int k = 0; k < EPT; ++k) {
      int e = base + k * 256;
      if (e < NE) {
        int d = dst[e];
        int s = src[e];
        int bk = d >> 8;
        int slot = boff[bk] + (int)meta_lp[k * 256 + t];
        stage[slot] = ((uint)s << 8) | (uint)(d & 255);
        sbuck[slot] = (unsigned char)bk;
      }
    }
    __syncthreads();
    // phase 5: contiguous-run writes
    int ntot = scan[255];
    for (int i = t; i < ntot; i += 256) {
      int b = sbuck[i];
      int pos = gbase[b] + (i - boff[b]);
      if (pos < BCAP) ebuf[(size_t)b * BCAP + pos] = stage[i];
    }
  }
}

// ---------- bucket -> ELL + deg, all scatter in LDS, all global I/O coalesced ----------
__global__ __launch_bounds__(256) void ellbuild_k(const int* __restrict__ cursor, const uint* __restrict__ ebuf,
                                                  int* __restrict__ deg, ushort* __restrict__ ell) {
  __shared__ ushort lell[256 * ELLW];
  __shared__ int lcnt[256];
  int t = threadIdx.x;
  int b = blockIdx.x;
  lcnt[t] = 0;
  __syncthreads();
  int ne = cursor[b * CSTRIDE];
  if (ne > BCAP) ne = BCAP;
  for (int i = t; i < ne; i += 256) {
    uint u = ebuf[(size_t)b * BCAP + i];
    int dl = u & 255;
    int p = atomicAdd(&lcnt[dl], 1);
    if (p < ELLW) lell[dl * ELLW + p] = (ushort)(u >> 8);
  }
  __syncthreads();
  int node = b * 256 + t;
  if (node < NN) deg[node] = lcnt[t];
  const uint* l4 = (const uint*)lell;
  uint* g4 = (uint*)ell;
  for (int idx = t; idx < 256 * 32; idx += 256) {
    int nod = b * 256 + (idx >> 5);
    if (nod < NN) g4[(size_t)nod * 32 + (idx & 31)] = l4[idx];
  }
}

// ---------- GEMM (layer 2): stages bf16 h1 -> f32 LDS, scaled bf16 out ----------
__global__ __launch_bounds__(256) void gemm128_k(const ushort* __restrict__ H, const float* __restrict__ W,
                                                 const int* __restrict__ deg, ushort* __restrict__ out) {
  __shared__ float xs[64 * 128];
  int t = threadIdx.x;
  int row0 = blockIdx.x * 64;
  const uint* H2 = (const uint*)H;
#pragma unroll
  for (int i = 0; i < 16; ++i) {
    int idx = i * 256 + t;
    int r = row0 + (idx >> 6);
    if (r > NN - 1) r = NN - 1;
    int c = idx & 63;
    uint u = H2[(size_t)r * 64 + c];
    float2 f;
    f.x = __uint_as_float(u << 16);
    f.y = __uint_as_float(u & 0xffff0000u);
    *(float2*)&xs[(idx >> 6) * 128 + c * 2] = f;
  }
  __syncthreads();
  gemm_tile(xs, W, deg, out, row0, t, true);
}

// ---------- pull aggregation (measured structure, unchanged) ----------
template <bool POOL, bool SSRC>
__global__ __launch_bounds__(256) void aggregate_k(const ushort* __restrict__ tmp2,
                                                   const ushort* __restrict__ ell, const int* __restrict__ deg,
                                                   const float* __restrict__ bias,
                                                   ushort* __restrict__ out,
                                                   const int* __restrict__ batch, float* __restrict__ sums) {
  int wid = threadIdx.x >> 6;
  int lane = threadIdx.x & 63;
  int n = blockIdx.x * 4 + wid;
  if (n >= NN) return;
  const uint* TU = (const uint*)tmp2;
  int dn = deg[n];
  float dv = rsqrtf((float)(dn + 1));
  uint sv = TU[(size_t)n * 64 + lane];
  float sw = SSRC ? dv : 1.0f;
  float2 acc;
  acc.x = __uint_as_float(sv << 16) * sw;
  acc.y = __uint_as_float(sv & 0xffff0000u) * sw;
  int d = dn; if (d > ELLW) d = ELLW;
  int idx = (int)ell[(size_t)n * ELLW + lane];
  int j = 0;
  for (; j + 8 <= d; j += 8) {
    int s0 = __shfl(idx, j);
    int s1 = __shfl(idx, j + 1);
    int s2 = __shfl(idx, j + 2);
    int s3 = __shfl(idx, j + 3);
    int s4 = __shfl(idx, j + 4);
    int s5 = __shfl(idx, j + 5);
    int s6 = __shfl(idx, j + 6);
    int s7 = __shfl(idx, j + 7);
    float d0 = SSRC ? rsqrtf((float)(deg[s0] + 1)) : 1.0f;
    float d1 = SSRC ? rsqrtf((float)(deg[s1] + 1)) : 1.0f;
    float d2 = SSRC ? rsqrtf((float)(deg[s2] + 1)) : 1.0f;
    float d3 = SSRC ? rsqrtf((float)(deg[s3] + 1)) : 1.0f;
    float d4 = SSRC ? rsqrtf((float)(deg[s4] + 1)) : 1.0f;
    float d5 = SSRC ? rsqrtf((float)(deg[s5] + 1)) : 1.0f;
    float d6 = SSRC ? rsqrtf((float)(deg[s6] + 1)) : 1.0f;
    float d7 = SSRC ? rsqrtf((float)(deg[s7] + 1)) : 1.0f;
    uint v0 = TU[(size_t)s0 * 64 + lane];
    uint v1 = TU[(size_t)s1 * 64 + lane];
    uint v2 = TU[(size_t)s2 * 64 + lane];
    uint v3 = TU[(size_t)s3 * 64 + lane];
    uint v4 = TU[(size_t)s4 * 64 + lane];
    uint v5 = TU[(size_t)s5 * 64 + lane];
    uint v6 = TU[(size_t)s6 * 64 + lane];
    uint v7 = TU[(size_t)s7 * 64 + lane];
    if (SSRC) {
      acc.x = fmaf(__uint_as_float(v0 << 16), d0, acc.x);
      acc.y = fmaf(__uint_as_float(v0 & 0xffff0000u), d0, acc.y);
      acc.x = fmaf(__uint_as_float(v1 << 16), d1, acc.x);
      acc.y = fmaf(__uint_as_float(v1 & 0xffff0000u), d1, acc.y);
      acc.x = fmaf(__uint_as_float(v2 << 16), d2, acc.x);
      acc.y = fmaf(__uint_as_float(v2 & 0xffff0000u), d2, acc.y);
      acc.x = fmaf(__uint_as_float(v3 << 16), d3, acc.x);
      acc.y = fmaf(__uint_as_float(v3 & 0xffff0000u), d3, acc.y);
      acc.x = fmaf(__uint_as_float(v4 << 16), d4, acc.x);
      acc.y = fmaf(__uint_as_float(v4 & 0xffff0000u), d4, acc.y);
      acc.x = fmaf(__uint_as_float(v5 << 16), d5, acc.x);
      acc.y = fmaf(__uint_as_float(v5 & 0xffff0000u), d5, acc.y);
      acc.x = fmaf(__uint_as_float(v6 << 16), d6, acc.x);
      acc.y = fmaf(__uint_as_float(v6 & 0xffff0000u), d6, acc.y);
      acc.x = fmaf(__uint_as_float(v7 << 16), d7, acc.x);
      acc.y = fmaf(__uint_as_float(v7 & 0xffff0000u), d7, acc.y);
    } else {
      float x0 = __uint_as_float(v0 << 16), y0 = __uint_as_float(v0 & 0xffff0000u);
      float x1 = __uint_as_float(v1 << 16), y1 = __uint_as_float(v1 & 0xffff0000u);
      float x2 = __uint_as_float(v2 << 16), y2 = __uint_as_float(v2 & 0xffff0000u);
      float x3 = __uint_as_float(v3 << 16), y3 = __uint_as_float(v3 & 0xffff0000u);
      float x4 = __uint_as_float(v4 << 16), y4 = __uint_as_float(v4 & 0xffff0000u);
      float x5 = __uint_as_float(v5 << 16), y5 = __uint_as_float(v5 & 0xffff0000u);
      float x6 = __uint_as_float(v6 << 16), y6 = __uint_as_float(v6 & 0xffff0000u);
      float x7 = __uint_as_float(v7 << 16), y7 = __uint_as_float(v7 & 0xffff0000u);
      acc.x += ((x0 + x1) + (x2 + x3)) + ((x4 + x5) + (x6 + x7));
      acc.y += ((y0 + y1) + (y2 + y3)) + ((y4 + y5) + (y6 + y7));
    }
  }
  for (; j < d; ++j) {
    int s0 = __shfl(idx, j);
    float d0 = SSRC ? rsqrtf((float)(deg[s0] + 1)) : 1.0f;
    uint v = TU[(size_t)s0 * 64 + lane];
    acc.x = fmaf(__uint_as_float(v << 16), d0, acc.x);
    acc.y = fmaf(__uint_as_float(v & 0xffff0000u), d0, acc.y);
  }
  float2 bb = ((const float2*)bias)[lane];
  float ox = fmaxf(fmaf(acc.x, dv, bb.x), 0.0f);
  float oy = fmaxf(fmaf(acc.y, dv, bb.y), 0.0f);
  if (POOL) {
    int g = batch[n];
    float* sp = &sums[(size_t)g * HD + lane * 2];
    atomicAdd(sp + 0, ox);
    atomicAdd(sp + 1, oy);
  } else {
    uint pk = f32_to_bf16_rne(ox) | (f32_to_bf16_rne(oy) << 16);
    ((uint*)out)[(size_t)n * 64 + lane] = pk;
  }
}

// ---------- head ----------
__global__ __launch_bounds__(128) void mlp_k(const float* __restrict__ sums, const int* __restrict__ cnt,
                                             const float* __restrict__ Wl1, const float* __restrict__ bl1,
                                             const float* __restrict__ Wl2, const float* __restrict__ bl2,
                                             float* __restrict__ out) {
  __shared__ float gs[128];
  __shared__ float red[128];
  int g = blockIdx.x, t = threadIdx.x;
  int c = cnt[g]; if (c < 1) c = 1;
  gs[t] = sums[(size_t)g * HD + t] / (float)c;
  __syncthreads();
  float acc = bl1[t];
#pragma unroll 8
  for (int k = 0; k < 128; ++k) acc = fmaf(gs[k], Wl1[k * HD + t], acc);
  acc = fmaxf(acc, 0.0f);
  red[t] = acc * Wl2[t];
  __syncthreads();
  for (int off = 64; off > 0; off >>= 1) {
    if (t < off) red[t] += red[t + off];
    __syncthreads();
  }
  if (t == 0) out[g] = red[0] + bl2[0];
}

extern "C" void kernel_launch(void* const* d_in, const int* in_sizes, int n_in,
                              void* d_out, int out_size, void* d_ws, size_t ws_size,
                              hipStream_t stream) {
  const float* x   = (const float*)d_in[0];
  const int*   edge = (const int*)d_in[1];
  const int*   batch = (const int*)d_in[2];
  const float* W1  = (const float*)d_in[3];
  const float* b1  = (const float*)d_in[4];
  const float* W2  = (const float*)d_in[5];
  const float* b2  = (const float*)d_in[6];
  const float* Wl1 = (const float*)d_in[7];
  const float* bl1 = (const float*)d_in[8];
  const float* Wl2 = (const float*)d_in[9];
  const float* bl2 = (const float*)d_in[10];
  const int* srcp = edge;
  const int* dstp = edge + NE;

  char* w = (char*)d_ws;
  size_t off = 0;
  auto alloc = [&](size_t bytes) -> void* {
    void* p = w + off;
    off += (bytes + 255) & ~(size_t)255;
    return p;
  };
  // zero region: cursor | cnt | sums (one memset)
  int*    cursor = (int*)alloc((size_t)NBUCK * CSTRIDE * 4);
  int*    cnt    = (int*)alloc(NG * 4);
  float*  sums   = (float*)alloc((size_t)NG * HD * 4);
  size_t zero_bytes = off;
  int*    deg  = (int*)alloc(NN * 4);
  uint*   ebuf = (uint*)alloc((size_t)NBUCK * BCAP * 4);
  ushort* ell  = (ushort*)alloc((size_t)NN * ELLW * 2);
  ushort* tmp  = (ushort*)alloc((size_t)NN * HD * 2);   // bf16 layer-1 out (UNSCALED)
  ushort* h1   = (ushort*)alloc((size_t)NN * HD * 2);   // bf16 h1
  ushort* tmp2 = (ushort*)alloc((size_t)NN * HD * 2);   // bf16 layer-2 out (scaled)

  hipMemsetAsync(cursor, 0, zero_bytes, stream);

  scatter_gemm_k<<<NB_GEMM + NB_SCAT, 256, 0, stream>>>(x, W1, tmp, srcp, dstp, batch, cursor, ebuf, cnt);
  ellbuild_k<<<NBUCK, 256, 0, stream>>>(cursor, ebuf, deg, ell);
  aggregate_k<false, true><<<(NN + 3) / 4, 256, 0, stream>>>(tmp, ell, deg, b1, h1, nullptr, nullptr);
  gemm128_k<<<(NN + 63) / 64, 256, 0, stream>>>(h1, W2, deg, tmp2);
  aggregate_k<true, false><<<(NN + 3) / 4, 256, 0, stream>>>(tmp2, ell, deg, b2, nullptr, batch, sums);
  mlp_k<<<NG, 128, 0, stream>>>(sums, cnt, Wl1, bl1, Wl2, bl2, (float*)d_out);
}

// Round 23
// 180.307 us; speedup vs baseline: 1.3345x; 1.2569x over previous
//
#include <hip/hip_runtime.h>

#define NN 50000
#define NE 800000
#define HD 128
#define NG 256
#define ELLW 64
#define NBUCK 196           /* ceil(50000/256) buckets of 256 nodes */
#define BCAP 4736           /* bucket capacity: mean 4096, +10 sigma */
#define CSTRIDE 16          /* cursor padding: one per 64B line */
#define EPT 8               /* edges per thread in scatter blocks */
#define EPB (256 * EPT)     /* 2048 edges per scatter block */
#define NB_GEMM ((NN + 63) / 64)
#define NB_SCAT ((NE + EPB - 1) / EPB)

__device__ __forceinline__ unsigned f32_to_bf16_rne(float f) {
  unsigned u = __float_as_uint(f);
  return (u + 0x7fffu + ((u >> 16) & 1u)) >> 16;
}

// gemm tile compute from f32 LDS tile: out_bf16[r][c] = bf16((xs@W)[r][c] * (scale?rsqrt(deg[r]+1):1))
__device__ __forceinline__ void gemm_tile(const float* xs, const float* __restrict__ W,
                                          const int* __restrict__ deg, ushort* __restrict__ out,
                                          int row0, int t, bool scale) {
  int lane = t & 31;
  int rg = t >> 5;
  const float4* W4 = (const float4*)W;
  float acc[8][4] = {};
#pragma unroll 2
  for (int k = 0; k < 128; k += 4) {
    float4 b[4];
#pragma unroll
    for (int kk = 0; kk < 4; ++kk) b[kk] = W4[(size_t)(k + kk) * 32 + lane];
    float4 a[8];
#pragma unroll
    for (int i = 0; i < 8; ++i) a[i] = *(const float4*)&xs[(rg * 8 + i) * 128 + k];
#pragma unroll
    for (int i = 0; i < 8; ++i) {
      acc[i][0] = fmaf(a[i].x, b[0].x, acc[i][0]);
      acc[i][1] = fmaf(a[i].x, b[0].y, acc[i][1]);
      acc[i][2] = fmaf(a[i].x, b[0].z, acc[i][2]);
      acc[i][3] = fmaf(a[i].x, b[0].w, acc[i][3]);
      acc[i][0] = fmaf(a[i].y, b[1].x, acc[i][0]);
      acc[i][1] = fmaf(a[i].y, b[1].y, acc[i][1]);
      acc[i][2] = fmaf(a[i].y, b[1].z, acc[i][2]);
      acc[i][3] = fmaf(a[i].y, b[1].w, acc[i][3]);
      acc[i][0] = fmaf(a[i].z, b[2].x, acc[i][0]);
      acc[i][1] = fmaf(a[i].z, b[2].y, acc[i][1]);
      acc[i][2] = fmaf(a[i].z, b[2].z, acc[i][2]);
      acc[i][3] = fmaf(a[i].z, b[2].w, acc[i][3]);
      acc[i][0] = fmaf(a[i].w, b[3].x, acc[i][0]);
      acc[i][1] = fmaf(a[i].w, b[3].y, acc[i][1]);
      acc[i][2] = fmaf(a[i].w, b[3].z, acc[i][2]);
      acc[i][3] = fmaf(a[i].w, b[3].w, acc[i][3]);
    }
  }
#pragma unroll
  for (int i = 0; i < 8; ++i) {
    int r = row0 + rg * 8 + i;
    if (r < NN) {
      float d = scale ? rsqrtf((float)(deg[r] + 1)) : 1.0f;
      ushort4 o;
      o.x = (ushort)f32_to_bf16_rne(acc[i][0] * d);
      o.y = (ushort)f32_to_bf16_rne(acc[i][1] * d);
      o.z = (ushort)f32_to_bf16_rne(acc[i][2] * d);
      o.w = (ushort)f32_to_bf16_rne(acc[i][3] * d);
      *(ushort4*)&out[(size_t)r * 128 + lane * 4] = o;
    }
  }
}

// ---------- heterogeneous: gemm1 blocks first; LDS-binning scatter blocks backfill ----------
// Scatter block: 2048 edges. Phase 2 stores payload + (bk,lp) meta in LDS (one
// global read of src/dst total). Block-scan, ONE global atomic per (block,bucket),
// LDS-only reorder into bucket-sorted stage, contiguous-run global writes.
__global__ __launch_bounds__(256) void scatter_gemm_k(const float* __restrict__ X, const float* __restrict__ W1,
                                                      ushort* __restrict__ tmp,
                                                      const int* __restrict__ src, const int* __restrict__ dst,
                                                      int* __restrict__ cursor, uint* __restrict__ ebuf) {
  __shared__ __align__(16) char smem[32768];
  int t = threadIdx.x;
  if (blockIdx.x < NB_GEMM) {
    float* xs = (float*)smem;
    int row0 = blockIdx.x * 64;
    const float4* X4 = (const float4*)X;
    float4* xs4 = (float4*)xs;
#pragma unroll
    for (int i = 0; i < 8; ++i) {
      int idx = i * 256 + t;
      int r = row0 + (idx >> 5);
      if (r > NN - 1) r = NN - 1;
      xs4[idx] = X4[(size_t)r * 32 + (idx & 31)];
    }
    __syncthreads();
    gemm_tile(xs, W1, nullptr, tmp, row0, t, false);
  } else {
    uint*   stage   = (uint*)smem;                 // [2048]  0..8K
    uint*   payload = (uint*)(smem + 8192);        // [2048]  8K..16K
    uint*   meta    = (uint*)(smem + 16384);       // [2048] 16K..24K (bk<<16 | lp)
    unsigned char* sbuck = (unsigned char*)(smem + 24576); // [2048] 24K..26K
    int*    bcnt  = (int*)(smem + 26624);          // [256] 26K..27K
    int*    scan  = (int*)(smem + 27648);          // [256] 27K..28K
    int*    boff  = (int*)(smem + 28672);          // [256] 28K..29K
    int*    gbase = (int*)(smem + 29696);          // [256] 29K..30K
    bcnt[t] = 0;
    __syncthreads();
    int base = (blockIdx.x - NB_GEMM) * EPB + t;
    // phase 2: bin + stash payload/meta in LDS
#pragma unroll 4
    for (int k = 0; k < EPT; ++k) {
      int e = base + k * 256;
      if (e < NE) {
        int d = dst[e];
        int s = src[e];
        int bk = d >> 8;
        int lp = atomicAdd(&bcnt[bk], 1);
        payload[k * 256 + t] = ((uint)s << 8) | (uint)(d & 255);
        meta[k * 256 + t] = ((uint)bk << 16) | (uint)lp;
      }
    }
    __syncthreads();
    // phase 3: scan + reserve
    int v = bcnt[t];
    scan[t] = v;
    __syncthreads();
    for (int off = 1; off < 256; off <<= 1) {
      int x = (t >= off) ? scan[t - off] : 0;
      __syncthreads();
      scan[t] += x;
      __syncthreads();
    }
    boff[t] = scan[t] - v;
    if (t < NBUCK && v > 0) gbase[t] = atomicAdd(&cursor[t * CSTRIDE], v);
    __syncthreads();
    // phase 4: LDS-only reorder into bucket-sorted stage
#pragma unroll 4
    for (int k = 0; k < EPT; ++k) {
      int e = base + k * 256;
      if (e < NE) {
        uint m = meta[k * 256 + t];
        int bk = (int)(m >> 16);
        int lp = (int)(m & 0xffffu);
        int slot = boff[bk] + lp;
        stage[slot] = payload[k * 256 + t];
        sbuck[slot] = (unsigned char)bk;
      }
    }
    __syncthreads();
    // phase 5: contiguous-run writes
    int ntot = scan[255];
    for (int i = t; i < ntot; i += 256) {
      int b = sbuck[i];
      int pos = gbase[b] + (i - boff[b]);
      if (pos < BCAP) ebuf[(size_t)b * BCAP + pos] = stage[i];
    }
  }
}

// ---------- bucket -> ELL + deg (LDS scatter, coalesced I/O) + graph boundaries ----------
__global__ __launch_bounds__(256) void ellbuild_k(const int* __restrict__ cursor, const uint* __restrict__ ebuf,
                                                  const int* __restrict__ batch,
                                                  int* __restrict__ deg, ushort* __restrict__ ell,
                                                  int* __restrict__ gstart, int* __restrict__ gend) {
  __shared__ ushort lell[256 * ELLW];
  __shared__ int lcnt[256];
  int t = threadIdx.x;
  int b = blockIdx.x;
  lcnt[t] = 0;
  __syncthreads();
  int ne = cursor[b * CSTRIDE];
  if (ne > BCAP) ne = BCAP;
  for (int i = t; i < ne; i += 256) {
    uint u = ebuf[(size_t)b * BCAP + i];
    int dl = u & 255;
    int p = atomicAdd(&lcnt[dl], 1);
    if (p < ELLW) lell[dl * ELLW + p] = (ushort)(u >> 8);
  }
  __syncthreads();
  int node = b * 256 + t;
  if (node < NN) {
    deg[node] = lcnt[t];
    // batch is sorted: record graph boundaries (no atomics)
    int g = batch[node];
    if (node == 0 || batch[node - 1] != g) gstart[g] = node;
    if (node == NN - 1 || batch[node + 1] != g) gend[g] = node + 1;
  }
  const uint* l4 = (const uint*)lell;
  uint* g4 = (uint*)ell;
  for (int idx = t; idx < 256 * 32; idx += 256) {
    int nod = b * 256 + (idx >> 5);
    if (nod < NN) g4[(size_t)nod * 32 + (idx & 31)] = l4[idx];
  }
}

// ---------- GEMM (layer 2): stages bf16 h1 -> f32 LDS, scaled bf16 out ----------
__global__ __launch_bounds__(256) void gemm128_k(const ushort* __restrict__ H, const float* __restrict__ W,
                                                 const int* __restrict__ deg, ushort* __restrict__ out) {
  __shared__ float xs[64 * 128];
  int t = threadIdx.x;
  int row0 = blockIdx.x * 64;
  const uint* H2 = (const uint*)H;
#pragma unroll
  for (int i = 0; i < 16; ++i) {
    int idx = i * 256 + t;
    int r = row0 + (idx >> 6);
    if (r > NN - 1) r = NN - 1;
    int c = idx & 63;
    uint u = H2[(size_t)r * 64 + c];
    float2 f;
    f.x = __uint_as_float(u << 16);
    f.y = __uint_as_float(u & 0xffff0000u);
    *(float2*)&xs[(idx >> 6) * 128 + c * 2] = f;
  }
  __syncthreads();
  gemm_tile(xs, W, deg, out, row0, t, true);
}

// ---------- pull aggregation (measured structure, unchanged) ----------
template <bool POOL, bool SSRC>
__global__ __launch_bounds__(256) void aggregate_k(const ushort* __restrict__ tmp2,
                                                   const ushort* __restrict__ ell, const int* __restrict__ deg,
                                                   const float* __restrict__ bias,
                                                   ushort* __restrict__ out,
                                                   const int* __restrict__ batch, float* __restrict__ sums) {
  int wid = threadIdx.x >> 6;
  int lane = threadIdx.x & 63;
  int n = blockIdx.x * 4 + wid;
  if (n >= NN) return;
  const uint* TU = (const uint*)tmp2;
  int dn = deg[n];
  float dv = rsqrtf((float)(dn + 1));
  uint sv = TU[(size_t)n * 64 + lane];
  float sw = SSRC ? dv : 1.0f;
  float2 acc;
  acc.x = __uint_as_float(sv << 16) * sw;
  acc.y = __uint_as_float(sv & 0xffff0000u) * sw;
  int d = dn; if (d > ELLW) d = ELLW;
  int idx = (int)ell[(size_t)n * ELLW + lane];
  int j = 0;
  for (; j + 8 <= d; j += 8) {
    int s0 = __shfl(idx, j);
    int s1 = __shfl(idx, j + 1);
    int s2 = __shfl(idx, j + 2);
    int s3 = __shfl(idx, j + 3);
    int s4 = __shfl(idx, j + 4);
    int s5 = __shfl(idx, j + 5);
    int s6 = __shfl(idx, j + 6);
    int s7 = __shfl(idx, j + 7);
    float d0 = SSRC ? rsqrtf((float)(deg[s0] + 1)) : 1.0f;
    float d1 = SSRC ? rsqrtf((float)(deg[s1] + 1)) : 1.0f;
    float d2 = SSRC ? rsqrtf((float)(deg[s2] + 1)) : 1.0f;
    float d3 = SSRC ? rsqrtf((float)(deg[s3] + 1)) : 1.0f;
    float d4 = SSRC ? rsqrtf((float)(deg[s4] + 1)) : 1.0f;
    float d5 = SSRC ? rsqrtf((float)(deg[s5] + 1)) : 1.0f;
    float d6 = SSRC ? rsqrtf((float)(deg[s6] + 1)) : 1.0f;
    float d7 = SSRC ? rsqrtf((float)(deg[s7] + 1)) : 1.0f;
    uint v0 = TU[(size_t)s0 * 64 + lane];
    uint v1 = TU[(size_t)s1 * 64 + lane];
    uint v2 = TU[(size_t)s2 * 64 + lane];
    uint v3 = TU[(size_t)s3 * 64 + lane];
    uint v4 = TU[(size_t)s4 * 64 + lane];
    uint v5 = TU[(size_t)s5 * 64 + lane];
    uint v6 = TU[(size_t)s6 * 64 + lane];
    uint v7 = TU[(size_t)s7 * 64 + lane];
    if (SSRC) {
      acc.x = fmaf(__uint_as_float(v0 << 16), d0, acc.x);
      acc.y = fmaf(__uint_as_float(v0 & 0xffff0000u), d0, acc.y);
      acc.x = fmaf(__uint_as_float(v1 << 16), d1, acc.x);
      acc.y = fmaf(__uint_as_float(v1 & 0xffff0000u), d1, acc.y);
      acc.x = fmaf(__uint_as_float(v2 << 16), d2, acc.x);
      acc.y = fmaf(__uint_as_float(v2 & 0xffff0000u), d2, acc.y);
      acc.x = fmaf(__uint_as_float(v3 << 16), d3, acc.x);
      acc.y = fmaf(__uint_as_float(v3 & 0xffff0000u), d3, acc.y);
      acc.x = fmaf(__uint_as_float(v4 << 16), d4, acc.x);
      acc.y = fmaf(__uint_as_float(v4 & 0xffff0000u), d4, acc.y);
      acc.x = fmaf(__uint_as_float(v5 << 16), d5, acc.x);
      acc.y = fmaf(__uint_as_float(v5 & 0xffff0000u), d5, acc.y);
      acc.x = fmaf(__uint_as_float(v6 << 16), d6, acc.x);
      acc.y = fmaf(__uint_as_float(v6 & 0xffff0000u), d6, acc.y);
      acc.x = fmaf(__uint_as_float(v7 << 16), d7, acc.x);
      acc.y = fmaf(__uint_as_float(v7 & 0xffff0000u), d7, acc.y);
    } else {
      float x0 = __uint_as_float(v0 << 16), y0 = __uint_as_float(v0 & 0xffff0000u);
      float x1 = __uint_as_float(v1 << 16), y1 = __uint_as_float(v1 & 0xffff0000u);
      float x2 = __uint_as_float(v2 << 16), y2 = __uint_as_float(v2 & 0xffff0000u);
      float x3 = __uint_as_float(v3 << 16), y3 = __uint_as_float(v3 & 0xffff0000u);
      float x4 = __uint_as_float(v4 << 16), y4 = __uint_as_float(v4 & 0xffff0000u);
      float x5 = __uint_as_float(v5 << 16), y5 = __uint_as_float(v5 & 0xffff0000u);
      float x6 = __uint_as_float(v6 << 16), y6 = __uint_as_float(v6 & 0xffff0000u);
      float x7 = __uint_as_float(v7 << 16), y7 = __uint_as_float(v7 & 0xffff0000u);
      acc.x += ((x0 + x1) + (x2 + x3)) + ((x4 + x5) + (x6 + x7));
      acc.y += ((y0 + y1) + (y2 + y3)) + ((y4 + y5) + (y6 + y7));
    }
  }
  for (; j < d; ++j) {
    int s0 = __shfl(idx, j);
    float d0 = SSRC ? rsqrtf((float)(deg[s0] + 1)) : 1.0f;
    uint v = TU[(size_t)s0 * 64 + lane];
    acc.x = fmaf(__uint_as_float(v << 16), d0, acc.x);
    acc.y = fmaf(__uint_as_float(v & 0xffff0000u), d0, acc.y);
  }
  float2 bb = ((const float2*)bias)[lane];
  float ox = fmaxf(fmaf(acc.x, dv, bb.x), 0.0f);
  float oy = fmaxf(fmaf(acc.y, dv, bb.y), 0.0f);
  if (POOL) {
    int g = batch[n];
    float* sp = &sums[(size_t)g * HD + lane * 2];
    atomicAdd(sp + 0, ox);
    atomicAdd(sp + 1, oy);
  } else {
    uint pk = f32_to_bf16_rne(ox) | (f32_to_bf16_rne(oy) << 16);
    ((uint*)out)[(size_t)n * 64 + lane] = pk;
  }
}

// ---------- head ----------
__global__ __launch_bounds__(128) void mlp_k(const float* __restrict__ sums,
                                             const int* __restrict__ gstart, const int* __restrict__ gend,
                                             const float* __restrict__ Wl1, const float* __restrict__ bl1,
                                             const float* __restrict__ Wl2, const float* __restrict__ bl2,
                                             float* __restrict__ out) {
  __shared__ float gs[128];
  __shared__ float red[128];
  int g = blockIdx.x, t = threadIdx.x;
  int c = gend[g] - gstart[g]; if (c < 1) c = 1;
  gs[t] = sums[(size_t)g * HD + t] / (float)c;
  __syncthreads();
  float acc = bl1[t];
#pragma unroll 8
  for (int k = 0; k < 128; ++k) acc = fmaf(gs[k], Wl1[k * HD + t], acc);
  acc = fmaxf(acc, 0.0f);
  red[t] = acc * Wl2[t];
  __syncthreads();
  for (int off = 64; off > 0; off >>= 1) {
    if (t < off) red[t] += red[t + off];
    __syncthreads();
  }
  if (t == 0) out[g] = red[0] + bl2[0];
}

extern "C" void kernel_launch(void* const* d_in, const int* in_sizes, int n_in,
                              void* d_out, int out_size, void* d_ws, size_t ws_size,
                              hipStream_t stream) {
  const float* x   = (const float*)d_in[0];
  const int*   edge = (const int*)d_in[1];
  const int*   batch = (const int*)d_in[2];
  const float* W1  = (const float*)d_in[3];
  const float* b1  = (const float*)d_in[4];
  const float* W2  = (const float*)d_in[5];
  const float* b2  = (const float*)d_in[6];
  const float* Wl1 = (const float*)d_in[7];
  const float* bl1 = (const float*)d_in[8];
  const float* Wl2 = (const float*)d_in[9];
  const float* bl2 = (const float*)d_in[10];
  const int* srcp = edge;
  const int* dstp = edge + NE;

  char* w = (char*)d_ws;
  size_t off = 0;
  auto alloc = [&](size_t bytes) -> void* {
    void* p = w + off;
    off += (bytes + 255) & ~(size_t)255;
    return p;
  };
  // zero region: cursor | gstart | gend | sums (one memset)
  int*    cursor = (int*)alloc((size_t)NBUCK * CSTRIDE * 4);
  int*    gstart = (int*)alloc(NG * 4);
  int*    gend   = (int*)alloc(NG * 4);
  float*  sums   = (float*)alloc((size_t)NG * HD * 4);
  size_t zero_bytes = off;
  int*    deg  = (int*)alloc(NN * 4);
  uint*   ebuf = (uint*)alloc((size_t)NBUCK * BCAP * 4);
  ushort* ell  = (ushort*)alloc((size_t)NN * ELLW * 2);
  ushort* tmp  = (ushort*)alloc((size_t)NN * HD * 2);   // bf16 layer-1 out (UNSCALED)
  ushort* h1   = (ushort*)alloc((size_t)NN * HD * 2);   // bf16 h1
  ushort* tmp2 = (ushort*)alloc((size_t)NN * HD * 2);   // bf16 layer-2 out (scaled)

  hipMemsetAsync(cursor, 0, zero_bytes, stream);

  scatter_gemm_k<<<NB_GEMM + NB_SCAT, 256, 0, stream>>>(x, W1, tmp, srcp, dstp, cursor, ebuf);
  ellbuild_k<<<NBUCK, 256, 0, stream>>>(cursor, ebuf, batch, deg, ell, gstart, gend);
  aggregate_k<false, true><<<(NN + 3) / 4, 256, 0, stream>>>(tmp, ell, deg, b1, h1, nullptr, nullptr);
  gemm128_k<<<(NN + 63) / 64, 256, 0, stream>>>(h1, W2, deg, tmp2);
  aggregate_k<true, false><<<(NN + 3) / 4, 256, 0, stream>>>(tmp2, ell, deg, b2, nullptr, batch, sums);
  mlp_k<<<NG, 128, 0, stream>>>(sums, gstart, gend, Wl1, bl1, Wl2, bl2, (float*)d_out);
}